// Round 13
// baseline (2186.804 us; speedup 1.0000x reference)
//
#include <hip/hip_runtime.h>
#include <hip/hip_bf16.h>

#define NNODES 100000
#define NEDGES 1600000
#define IN_F 16
#define HID 128
#define NLAYERS 8
#define BN_EPS 1e-5f
#define BLOBSZ 532480   // ushorts per blob half: 8192 + 16*32768

typedef __attribute__((ext_vector_type(8))) short short8;
typedef __attribute__((ext_vector_type(4))) float f32x4;
typedef __attribute__((ext_vector_type(4))) unsigned int uint32x4;
typedef unsigned short ushort_t;
typedef unsigned int uint_t;

__device__ __forceinline__ ushort_t f2bf(float f) {   // RNE, unbiased
  uint_t u = __builtin_bit_cast(uint_t, f);
  uint_t r = (u + 0x7fffu + ((u >> 16) & 1u)) >> 16;
  return (ushort_t)r;
}
__device__ __forceinline__ float bfl(uint_t u) {
  return __builtin_bit_cast(float, u << 16);
}
__device__ __forceinline__ float bfh(uint_t u) {
  return __builtin_bit_cast(float, u & 0xFFFF0000u);
}
__device__ __forceinline__ void bsplit(float v, ushort_t& h, ushort_t& l) {
  h = f2bf(v);
  float r = v - bfl((uint_t)h);
  l = f2bf(r);
}

// nontemporal helpers (GEMM A/C streams only; agg stays cached — r10 lesson)
__device__ __forceinline__ f32x4 ntl4(const float* p) {
  return __builtin_nontemporal_load((const f32x4*)p);
}
__device__ __forceinline__ void nts1(float v, float* p) {
  __builtin_nontemporal_store(v, p);
}

// cheap truncation split of 8 fp32 -> hi/lo short8 (err <= 2^-16 rel)
__device__ __forceinline__ void split8(const float* v, short8& h8, short8& l8) {
  uint_t hp[4], lp[4];
#pragma unroll
  for (int j = 0; j < 4; ++j) {
    float v0 = v[2 * j], v1 = v[2 * j + 1];
    uint_t u0 = __builtin_bit_cast(uint_t, v0);
    uint_t u1 = __builtin_bit_cast(uint_t, v1);
    uint_t h0 = u0 & 0xFFFF0000u;
    uint_t h1 = u1 & 0xFFFF0000u;
    float r0 = v0 - __builtin_bit_cast(float, h0);
    float r1 = v1 - __builtin_bit_cast(float, h1);
    hp[j] = (h0 >> 16) | h1;
    lp[j] = (__builtin_bit_cast(uint_t, r0) >> 16) |
            (__builtin_bit_cast(uint_t, r1) & 0xFFFF0000u);
  }
  h8 = __builtin_bit_cast(short8, (uint32x4){hp[0], hp[1], hp[2], hp[3]});
  l8 = __builtin_bit_cast(short8, (uint32x4){lp[0], lp[1], lp[2], lp[3]});
}

// ===================== CSR build: 2-level bucket sort (r8 win) =====================
__global__ __launch_bounds__(256) void bhist_kernel(
    const int* __restrict__ dst, int* __restrict__ bucketCnt, int E, int nbk) {
  __shared__ int cnt[256];
  int t = threadIdx.x;
  cnt[t] = 0;
  __syncthreads();
  int base = blockIdx.x * 2048 + t * 8;
#pragma unroll
  for (int j = 0; j < 8; ++j) {
    int i = base + j;
    if (i < E) atomicAdd(&cnt[dst[i] >> 9], 1);
  }
  __syncthreads();
  if (t < nbk && cnt[t]) atomicAdd(&bucketCnt[t], cnt[t]);
}

__global__ void bscan_kernel(const int* __restrict__ bucketCnt, int* __restrict__ bucketBase,
                             int* __restrict__ bucketCur, int* __restrict__ row_ptr,
                             int N, int E, int nbk) {
  __shared__ int s[256];
  int t = threadIdx.x;
  s[t] = (t < nbk) ? bucketCnt[t] : 0;
  __syncthreads();
  for (int off = 1; off < 256; off <<= 1) {
    int v = (t >= off) ? s[t - off] : 0;
    __syncthreads();
    s[t] += v;
    __syncthreads();
  }
  int excl = (t == 0) ? 0 : s[t - 1];
  if (t < nbk) { bucketBase[t] = excl; bucketCur[t] = excl; }
  if (t == nbk) bucketBase[t] = E;
  if (t == 0) row_ptr[N] = E;
}

__global__ __launch_bounds__(256) void bscatter_kernel(
    const int* __restrict__ src, const int* __restrict__ dst,
    int* __restrict__ bucketCur, int2* __restrict__ ebuf, int E, int nbk) {
  __shared__ int cnt[256];
  __shared__ int base_l[256];
  int t = threadIdx.x;
  cnt[t] = 0;
  __syncthreads();
  int base = blockIdx.x * 2048 + t * 8;
  int bj[8], lr[8], dj[8], sj[8];
#pragma unroll
  for (int j = 0; j < 8; ++j) {
    int i = base + j;
    if (i < E) {
      dj[j] = dst[i];
      sj[j] = src[i];
      bj[j] = dj[j] >> 9;
      lr[j] = atomicAdd(&cnt[bj[j]], 1);
    } else bj[j] = -1;
  }
  __syncthreads();
  if (t < nbk) base_l[t] = cnt[t] ? atomicAdd(&bucketCur[t], cnt[t]) : 0;
  __syncthreads();
#pragma unroll
  for (int j = 0; j < 8; ++j)
    if (bj[j] >= 0) ebuf[base_l[bj[j]] + lr[j]] = make_int2(dj[j], sj[j]);
}

__global__ __launch_bounds__(256) void bcsr_kernel(
    const int2* __restrict__ ebuf, const int* __restrict__ bucketBase,
    int* __restrict__ row_ptr, int* __restrict__ colb, int N) {
  __shared__ int h[512];
  __shared__ int cur[512];
  __shared__ int s2[256];
  int b = blockIdx.x, t = threadIdx.x;
  int beg = bucketBase[b], end = bucketBase[b + 1];
  h[t] = 0; h[t + 256] = 0;
  __syncthreads();
  for (int p = beg + t; p < end; p += 256) atomicAdd(&h[ebuf[p].x & 511], 1);
  __syncthreads();
  s2[t] = h[2 * t] + h[2 * t + 1];
  __syncthreads();
  for (int off = 1; off < 256; off <<= 1) {
    int v = (t >= off) ? s2[t - off] : 0;
    __syncthreads();
    s2[t] += v;
    __syncthreads();
  }
  int ep = (t == 0) ? 0 : s2[t - 1];
  cur[2 * t] = ep;
  cur[2 * t + 1] = ep + h[2 * t];
  int dg = (b << 9) + 2 * t;
  if (dg < N) row_ptr[dg] = beg + cur[2 * t];
  if (dg + 1 < N) row_ptr[dg + 1] = beg + cur[2 * t + 1];
  __syncthreads();
  for (int p = beg + t; p < end; p += 256) {
    int2 e2 = ebuf[p];
    int pos = beg + atomicAdd(&cur[e2.x & 511], 1);
    colb[pos] = e2.y;
  }
}

// =================== weight pre-convert: split hi/lo MFMA-frag blobs ===================
__global__ void preconv_kernel(const float* __restrict__ W1_0, const float* __restrict__ W1,
                               const float* __restrict__ W2, const float* __restrict__ Wr1,
                               ushort_t* __restrict__ WB) {
  int g = blockIdx.y;
  int e = blockIdx.x * 256 + threadIdx.x;
  int KP = (g == 0) ? 32 : 128;
  if (e >= KP * 128) return;
  int k = e >> 7, n = e & 127;
  float v;
  if (g == 0) v = (k < 16) ? W1_0[k * 128 + n] : 0.0f;
  else if (g <= 7) v = W1[(size_t)(g - 1) * 16384 + e];
  else if (g <= 15) v = W2[(size_t)(g - 8) * 16384 + e];
  else v = Wr1[e];
  size_t base = (g == 0) ? 0 : (8192 + (size_t)(g - 1) * 32768);
  int unit = ((k >> 5) << 9) + ((n >> 4) << 6) + (n & 15) + (((k >> 3) & 3) << 4);
  ushort_t h, l;
  bsplit(v, h, l);
  WB[base + (size_t)unit * 8 + (k & 7)] = h;
  WB[BLOBSZ + base + (size_t)unit * 8 + (k & 7)] = l;
}

// ============================ layer-0 aggregation (F=16, fp32) ============================
__global__ __launch_bounds__(256) void agg16_kernel(
    const float* __restrict__ X, const int* __restrict__ rp, const int* __restrict__ colb,
    const float* __restrict__ eps, float* __restrict__ Z, int N) {
  int g = threadIdx.x >> 3;
  int l = threadIdx.x & 7;
  int n = blockIdx.x * 32 + g;
  if (n >= N) return;
  float e = 1.0f + eps[0];
  const float2* X2 = (const float2*)X;
  float2 self = X2[(size_t)n * 8 + l];
  float2 acc = make_float2(self.x * e, self.y * e);
  float2 acc2 = make_float2(0.0f, 0.0f);
  int beg = rp[n], end = rp[n + 1];
  int p = beg;
  for (; p + 4 <= end; p += 4) {
    int s0 = colb[p], s1 = colb[p + 1], s2 = colb[p + 2], s3 = colb[p + 3];
    float2 v0 = X2[(size_t)s0 * 8 + l];
    float2 v1 = X2[(size_t)s1 * 8 + l];
    float2 v2 = X2[(size_t)s2 * 8 + l];
    float2 v3 = X2[(size_t)s3 * 8 + l];
    acc.x += v0.x; acc.y += v0.y;
    acc2.x += v1.x; acc2.y += v1.y;
    acc.x += v2.x; acc.y += v2.y;
    acc2.x += v3.x; acc2.y += v3.y;
  }
  for (; p < end; ++p) {
    int s = colb[p];
    float2 v = X2[(size_t)s * 8 + l];
    acc.x += v.x; acc.y += v.y;
  }
  acc.x += acc2.x; acc.y += acc2.y;
  ((float2*)Z)[(size_t)n * 8 + l] = acc;
}

// layers 1..7: Y bf16, per-node wave blocks — r9 EXACT form (measured best, 90 us).
// r8: never fuse w/ GEMM. r10: nt hints regressed. r12: grid-stride persistence regressed
// (straggler waves, occupancy 71->56%). This per-node max-occupancy form is the floor.
__global__ __launch_bounds__(256) void agg128_kernel(
    const ushort_t* __restrict__ Y, const float* __restrict__ av, const float* __restrict__ cv,
    const int* __restrict__ rp, const int* __restrict__ colb,
    const float* __restrict__ eps, int layer, float* __restrict__ Z,
    float* __restrict__ SKIP, int N) {
  int wv = threadIdx.x >> 6;
  int lane = threadIdx.x & 63;
  int n = blockIdx.x * 4 + wv;
  if (n >= N) return;
  float e = 1.0f + eps[layer];
  float2 a2 = *(const float2*)(av + lane * 2);
  float2 c2 = *(const float2*)(cv + lane * 2);
  const uint_t* Yu = (const uint_t*)Y;
  uint_t sv = Yu[(size_t)n * 64 + lane];
  float hx = fmaxf(fmaf(a2.x, bfl(sv), c2.x), 0.0f);
  float hy = fmaxf(fmaf(a2.y, bfh(sv), c2.y), 0.0f);
  if (SKIP) {
    float2* S2 = (float2*)SKIP;
    float2 s = S2[(size_t)n * 64 + lane];
    s.x += hx; s.y += hy;
    S2[(size_t)n * 64 + lane] = s;
  }
  float ax = hx * e, ay = hy * e;
  float bx = 0.0f, by = 0.0f, cx = 0.0f, cy = 0.0f, dx = 0.0f, dy = 0.0f;
  int beg = rp[n], end = rp[n + 1];
  int p = beg;
  for (; p + 8 <= end; p += 8) {
    int s0 = colb[p], s1 = colb[p + 1], s2 = colb[p + 2], s3 = colb[p + 3];
    int s4 = colb[p + 4], s5 = colb[p + 5], s6 = colb[p + 6], s7 = colb[p + 7];
    uint_t v0 = Yu[(size_t)s0 * 64 + lane];
    uint_t v1 = Yu[(size_t)s1 * 64 + lane];
    uint_t v2 = Yu[(size_t)s2 * 64 + lane];
    uint_t v3 = Yu[(size_t)s3 * 64 + lane];
    uint_t v4 = Yu[(size_t)s4 * 64 + lane];
    uint_t v5 = Yu[(size_t)s5 * 64 + lane];
    uint_t v6 = Yu[(size_t)s6 * 64 + lane];
    uint_t v7 = Yu[(size_t)s7 * 64 + lane];
    ax += fmaxf(fmaf(a2.x, bfl(v0), c2.x), 0.0f);
    ay += fmaxf(fmaf(a2.y, bfh(v0), c2.y), 0.0f);
    bx += fmaxf(fmaf(a2.x, bfl(v1), c2.x), 0.0f);
    by += fmaxf(fmaf(a2.y, bfh(v1), c2.y), 0.0f);
    cx += fmaxf(fmaf(a2.x, bfl(v2), c2.x), 0.0f);
    cy += fmaxf(fmaf(a2.y, bfh(v2), c2.y), 0.0f);
    dx += fmaxf(fmaf(a2.x, bfl(v3), c2.x), 0.0f);
    dy += fmaxf(fmaf(a2.y, bfh(v3), c2.y), 0.0f);
    ax += fmaxf(fmaf(a2.x, bfl(v4), c2.x), 0.0f);
    ay += fmaxf(fmaf(a2.y, bfh(v4), c2.y), 0.0f);
    bx += fmaxf(fmaf(a2.x, bfl(v5), c2.x), 0.0f);
    by += fmaxf(fmaf(a2.y, bfh(v5), c2.y), 0.0f);
    cx += fmaxf(fmaf(a2.x, bfl(v6), c2.x), 0.0f);
    cy += fmaxf(fmaf(a2.y, bfh(v6), c2.y), 0.0f);
    dx += fmaxf(fmaf(a2.x, bfl(v7), c2.x), 0.0f);
    dy += fmaxf(fmaf(a2.y, bfh(v7), c2.y), 0.0f);
  }
  for (; p < end; ++p) {
    int s = colb[p];
    uint_t v = Yu[(size_t)s * 64 + lane];
    ax += fmaxf(fmaf(a2.x, bfl(v), c2.x), 0.0f);
    ay += fmaxf(fmaf(a2.y, bfh(v), c2.y), 0.0f);
  }
  ax += bx + cx + dx;
  ay += by + cy + dy;
  ((float2*)Z)[(size_t)n * 64 + lane] = make_float2(ax, ay);
}

// ========== LDS-free split-bf16 MFMA GEMM — 64-row tiles (r13 experiment) ==========
// r10 structure (direct per-lane frags, nt A/C, shuffle epilogue) but TILE=64:
// each wave computes ONE 16-row MFMA tile (acc halves to 32 VGPRs), grid doubles to
// 1563 blocks -> ~2x waves in flight to hide A-load latency.
// MODE 0: op=A(fp32)   MODE 1: op=relu(pa*A+pc)
// MODE 2: op=0.25*(A(fp32 SKIP) + relu(pa*A2(bf16)+pc))   MODE 3: A fp32 [M,16], K=32 pad
// OUT 0: C fp32 (nt)   OUT 1: C bf16 (cached — next gather's hot buffer)
template <int KTOT, int MODE, int OUT>
__global__ __launch_bounds__(256, 4) void gemm_mfma(
    const float* __restrict__ A, const ushort_t* __restrict__ A2u,
    const ushort_t* __restrict__ Bhi, const ushort_t* __restrict__ Blo,
    const float* __restrict__ bias,
    const float* __restrict__ pa, const float* __restrict__ pc,
    void* __restrict__ Cv,
    float* __restrict__ gsum, float* __restrict__ gsq,
    float* __restrict__ aout, float* __restrict__ cout, int* __restrict__ cnt,
    const float* __restrict__ gamma, const float* __restrict__ beta,
    float invN, int M, int nb) {
  __shared__ float s_part[4][256];   // [wave][0..127]=sum, [128..255]=sumsq
  __shared__ int s_last;
  const int tid = threadIdx.x;
  const int w = tid >> 6;
  const int lane = tid & 63;
  const int ln = lane & 15;
  const int quad = lane >> 4;
  const int brow = blockIdx.x * 64;
  constexpr int AST = (MODE == 3) ? 16 : KTOT;

  int r0 = brow + (w << 4) + ln;  if (r0 >= M) r0 = M - 1;

  f32x4 acc[8];
#pragma unroll
  for (int ct = 0; ct < 8; ++ct) acc[ct] = (f32x4){0.0f, 0.0f, 0.0f, 0.0f};

  constexpr int KC = KTOT / 32;
#pragma unroll
  for (int kcl = 0; kcl < KC; ++kcl) {
    const int kb = (kcl << 5) + (quad << 3);
    float e0[8];
    if constexpr (MODE == 3) {
      if (kb < 16) {
        f32x4 a0 = ntl4(A + (size_t)r0 * AST + kb);
        f32x4 a1 = ntl4(A + (size_t)r0 * AST + kb + 4);
        e0[0] = a0.x; e0[1] = a0.y; e0[2] = a0.z; e0[3] = a0.w;
        e0[4] = a1.x; e0[5] = a1.y; e0[6] = a1.z; e0[7] = a1.w;
      } else {
#pragma unroll
        for (int j = 0; j < 8; ++j) e0[j] = 0.0f;
      }
    } else {
      f32x4 a0 = ntl4(A + (size_t)r0 * AST + kb);
      f32x4 a1 = ntl4(A + (size_t)r0 * AST + kb + 4);
      e0[0] = a0.x; e0[1] = a0.y; e0[2] = a0.z; e0[3] = a0.w;
      e0[4] = a1.x; e0[5] = a1.y; e0[6] = a1.z; e0[7] = a1.w;
      if constexpr (MODE == 1) {
        float4 p0 = *(const float4*)(pa + kb);
        float4 p1 = *(const float4*)(pa + kb + 4);
        float4 q0 = *(const float4*)(pc + kb);
        float4 q1 = *(const float4*)(pc + kb + 4);
        float pp[8] = {p0.x, p0.y, p0.z, p0.w, p1.x, p1.y, p1.z, p1.w};
        float qq[8] = {q0.x, q0.y, q0.z, q0.w, q1.x, q1.y, q1.z, q1.w};
#pragma unroll
        for (int j = 0; j < 8; ++j)
          e0[j] = fmaxf(fmaf(pp[j], e0[j], qq[j]), 0.0f);
      } else if constexpr (MODE == 2) {
        uint4 ya = *(const uint4*)(A2u + (size_t)r0 * 128 + kb);
        float4 p0 = *(const float4*)(pa + kb);
        float4 p1 = *(const float4*)(pa + kb + 4);
        float4 q0 = *(const float4*)(pc + kb);
        float4 q1 = *(const float4*)(pc + kb + 4);
        float y0a[8] = {bfl(ya.x), bfh(ya.x), bfl(ya.y), bfh(ya.y),
                        bfl(ya.z), bfh(ya.z), bfl(ya.w), bfh(ya.w)};
        float pp[8] = {p0.x, p0.y, p0.z, p0.w, p1.x, p1.y, p1.z, p1.w};
        float qq[8] = {q0.x, q0.y, q0.z, q0.w, q1.x, q1.y, q1.z, q1.w};
#pragma unroll
        for (int j = 0; j < 8; ++j)
          e0[j] = 0.25f * (e0[j] + fmaxf(fmaf(pp[j], y0a[j], qq[j]), 0.0f));
      }
    }
    short8 a0h, a0l;
    split8(e0, a0h, a0l);
    const ushort_t* bh_base = Bhi + (((size_t)(kcl << 9) + lane) << 3);
    const ushort_t* bl_base = Blo + (((size_t)(kcl << 9) + lane) << 3);
#pragma unroll
    for (int ct = 0; ct < 8; ++ct) {
      short8 bh = *(const short8*)(bh_base + (ct << 9));
      short8 bl = *(const short8*)(bl_base + (ct << 9));
      acc[ct] = __builtin_amdgcn_mfma_f32_16x16x32_bf16(a0h, bh, acc[ct], 0, 0, 0);
      acc[ct] = __builtin_amdgcn_mfma_f32_16x16x32_bf16(a0l, bh, acc[ct], 0, 0, 0);
      acc[ct] = __builtin_amdgcn_mfma_f32_16x16x32_bf16(a0h, bl, acc[ct], 0, 0, 0);
    }
  }

  // ---- epilogue: bias, store, quad-shuffle stats ----
#pragma unroll
  for (int ct = 0; ct < 8; ++ct) {
    int col = (ct << 4) + ln;
    float bsc = bias[col];
    float csum = 0.0f, csq = 0.0f;
#pragma unroll
    for (int i = 0; i < 4; ++i) {
      int row = brow + (w << 4) + (quad << 2) + i;
      if (row < M) {
        float y = acc[ct][i] + bsc;
        csum += y; csq += y * y;
        if constexpr (OUT == 0) {
          nts1(y, &((float*)Cv)[(size_t)row * 128 + col]);
        } else {
          ((ushort_t*)Cv)[(size_t)row * 128 + col] = f2bf(y);
        }
      }
    }
    csum += __shfl_xor(csum, 16, 64);
    csum += __shfl_xor(csum, 32, 64);
    csq += __shfl_xor(csq, 16, 64);
    csq += __shfl_xor(csq, 32, 64);
    if (quad == 0) {
      s_part[w][col] = csum;
      s_part[w][128 + col] = csq;
    }
  }
  __syncthreads();
  if (tid < 128) {
    float s = s_part[0][tid] + s_part[1][tid] + s_part[2][tid] + s_part[3][tid];
    float q = s_part[0][128 + tid] + s_part[1][128 + tid] +
              s_part[2][128 + tid] + s_part[3][128 + tid];
    atomicAdd(&gsum[tid], s);   // relaxed device-scope, no flush (r6)
    atomicAdd(&gsq[tid], q);
  }
  __syncthreads();   // drains vmcnt -> stats atomics complete
  if (tid == 0) {
    int v = __hip_atomic_fetch_add(cnt, 1, __ATOMIC_RELAXED, __HIP_MEMORY_SCOPE_AGENT);
    s_last = (v == nb - 1) ? 1 : 0;
  }
  __syncthreads();
  if (s_last && tid < 128) {
    float s = __hip_atomic_load(&gsum[tid], __ATOMIC_RELAXED, __HIP_MEMORY_SCOPE_AGENT);
    float q = __hip_atomic_load(&gsq[tid], __ATOMIC_RELAXED, __HIP_MEMORY_SCOPE_AGENT);
    float mu = s * invN;
    float var = q * invN - mu * mu;
    float sc = gamma[tid] * rsqrtf(var + BN_EPS);
    aout[tid] = sc;
    cout[tid] = beta[tid] - sc * mu;
  }
}

// ============================ regressor head ============================
__global__ __launch_bounds__(256) void finaldot_kernel(
    const float* __restrict__ Y, const float* __restrict__ a, const float* __restrict__ c,
    const float* __restrict__ Wr2, const float* __restrict__ br2,
    float* __restrict__ out, int N) {
  int wv = threadIdx.x >> 6;
  int lane = threadIdx.x & 63;
  int n = blockIdx.x * 4 + wv;
  if (n >= N) return;
  float2 y = *(const float2*)(Y + (size_t)n * HID + lane * 2);
  int c0 = lane * 2;
  float s = fmaxf(fmaf(a[c0], y.x, c[c0]), 0.0f) * Wr2[c0] +
            fmaxf(fmaf(a[c0 + 1], y.y, c[c0 + 1]), 0.0f) * Wr2[c0 + 1];
  for (int off = 32; off > 0; off >>= 1) s += __shfl_down(s, off, 64);
  if (lane == 0) out[n] = 1.0f / (1.0f + expf(-(s + br2[0])));
}

// ============================ launch ============================
extern "C" void kernel_launch(void* const* d_in, const int* in_sizes, int n_in,
                              void* d_out, int out_size, void* d_ws, size_t ws_size,
                              hipStream_t stream) {
  const float* x     = (const float*)d_in[0];
  const int*   ei    = (const int*)d_in[1];
  const float* eps   = (const float*)d_in[2];
  const float* W1_0  = (const float*)d_in[3];
  const float* b1_0  = (const float*)d_in[4];
  const float* W1    = (const float*)d_in[5];
  const float* b1    = (const float*)d_in[6];
  const float* g_in  = (const float*)d_in[7];
  const float* be_in = (const float*)d_in[8];
  const float* W2    = (const float*)d_in[9];
  const float* b2    = (const float*)d_in[10];
  const float* g_out = (const float*)d_in[11];
  const float* be_out= (const float*)d_in[12];
  const float* Wr1   = (const float*)d_in[13];
  const float* br1   = (const float*)d_in[14];
  const float* gr    = (const float*)d_in[15];
  const float* ber   = (const float*)d_in[16];
  const float* Wr2   = (const float*)d_in[17];
  const float* br2   = (const float*)d_in[18];
  float* out = (float*)d_out;

  const int N = in_sizes[0] / IN_F;   // 100000
  const int E = in_sizes[1] / 2;      // 1600000
  const int* srcv = ei;
  const int* dstv = ei + E;
  const int nbk = (N + 511) >> 9;     // 196 buckets

  // workspace carve
  float* X0    = (float*)d_ws;                  // [N][128] fp32 (Z / H1, in-place)
  float* SKIP  = X0 + (size_t)N * HID;          // [N][128] fp32 (layer-0 temp, then skip)
  ushort_t* YB = (ushort_t*)(SKIP + (size_t)N * HID);  // [N][128] bf16 Y (hot gather target)
  int* colb    = (int*)(YB + (size_t)N * HID);
  int* row_ptr = colb + E;
  int2* ebuf   = (int2*)(row_ptr + (N + 4));
  int* bucketCnt  = (int*)(ebuf + E);
  int* bucketBase = bucketCnt + 256;
  int* bucketCur  = bucketBase + 260;
  float* arena = (float*)(bucketCur + 256);     // 17 slots x 640 floats
  ushort_t* WB = (ushort_t*)(arena + 17 * 640); // hi blob | lo blob

  hipMemsetAsync(bucketCnt, 0, sizeof(int) * 256, stream);
  hipMemsetAsync(arena, 0, sizeof(float) * 17 * 640, stream);

  // CSR build (bucket sort)
  int nbE = (E + 2047) / 2048;
  bhist_kernel<<<nbE, 256, 0, stream>>>(dstv, bucketCnt, E, nbk);
  bscan_kernel<<<1, 256, 0, stream>>>(bucketCnt, bucketBase, bucketCur, row_ptr, N, E, nbk);
  bscatter_kernel<<<nbE, 256, 0, stream>>>(srcv, dstv, bucketCur, ebuf, E, nbk);
  bcsr_kernel<<<nbk, 256, 0, stream>>>(ebuf, bucketBase, row_ptr, colb, N);
  preconv_kernel<<<dim3(64, 17), 256, 0, stream>>>(W1_0, W1, W2, Wr1, WB);

  const int gg = (N + 63) / 64;   // 64-row tiles -> 1563 blocks
  const float invN = 1.0f / (float)N;
#define SLOT(s) (arena + (s) * 640)
#define SSUM(s) SLOT(s)
#define SSQ(s)  (SLOT(s) + 128)
#define SA(s)   (SLOT(s) + 256)
#define SC(s)   (SLOT(s) + 384)
#define SCNT(s) ((int*)(SLOT(s) + 512))
#define WBH(g)  (WB + ((g) == 0 ? 0 : (8192 + (size_t)((g) - 1) * 32768)))
#define WBL(g)  (WBH(g) + BLOBSZ)

  // ---- layer 0 ----  agg16: x -> X0[N,16]; g0a: X0 -> SKIP(temp); g0b: SKIP -> YB bf16
  agg16_kernel<<<(N + 31) / 32, 256, 0, stream>>>(x, row_ptr, colb, eps, X0, N);
  gemm_mfma<32, 3, 0><<<gg, 256, 0, stream>>>(
      X0, nullptr, WBH(0), WBL(0), b1_0, nullptr, nullptr, SKIP,
      SSUM(0), SSQ(0), SA(0), SC(0), SCNT(0), g_in, be_in, invN, N, gg);
  gemm_mfma<128, 1, 1><<<gg, 256, 0, stream>>>(
      SKIP, nullptr, WBH(8), WBL(8), b2, SA(0), SC(0), YB,
      SSUM(1), SSQ(1), SA(1), SC(1), SCNT(1), g_out, be_out, invN, N, gg);
  // SKIP now free; zero it for skip accumulation (stream-ordered)
  hipMemsetAsync(SKIP, 0, sizeof(float) * (size_t)N * HID, stream);

  // ---- layers 1..7 ----  agg: YB->X0 (fp32 Z); gemm1: X0->X0 in place; gemm2: X0->YB
  for (int L = 1; L < NLAYERS; ++L) {
    int sp = 2 * L - 1;
    int s0 = 2 * L, s1 = 2 * L + 1;
    float* skipw = ((L - 1) & 1) ? SKIP : nullptr;  // fold h_{L-1} at L=2,4,6
    agg128_kernel<<<(N + 3) / 4, 256, 0, stream>>>(
        YB, SA(sp), SC(sp), row_ptr, colb, eps, L, X0, skipw, N);
    gemm_mfma<128, 0, 0><<<gg, 256, 0, stream>>>(
        X0, nullptr, WBH(L), WBL(L), b1 + (size_t)(L - 1) * HID, nullptr, nullptr, X0,
        SSUM(s0), SSQ(s0), SA(s0), SC(s0), SCNT(s0),
        g_in + (size_t)L * HID, be_in + (size_t)L * HID, invN, N, gg);
    gemm_mfma<128, 1, 1><<<gg, 256, 0, stream>>>(
        X0, nullptr, WBH(8 + L), WBL(8 + L), b2 + (size_t)L * HID, SA(s0), SC(s0), YB,
        SSUM(s1), SSQ(s1), SA(s1), SC(s1), SCNT(s1),
        g_out + (size_t)L * HID, be_out + (size_t)L * HID, invN, N, gg);
  }
  // Y7 in YB (bf16), slot 15 holds its outer-BN params

  // ---- regressor: op = 0.25*(SKIP + relu(a7*Y7+c7)) ----
  gemm_mfma<128, 2, 0><<<gg, 256, 0, stream>>>(
      SKIP, YB, WBH(16), WBL(16), br1, SA(15), SC(15), X0,
      SSUM(16), SSQ(16), SA(16), SC(16), SCNT(16), gr, ber, invN, N, gg);
  finaldot_kernel<<<(N + 3) / 4, 256, 0, stream>>>(X0, SA(16), SC(16), Wr2, br2, out, N);
#undef SLOT
#undef SSUM
#undef SSQ
#undef SA
#undef SC
#undef SCNT
#undef WBH
#undef WBL
}

// Round 14
// 1732.965 us; speedup vs baseline: 1.2619x; 1.2619x over previous
//
#include <hip/hip_runtime.h>
#include <hip/hip_bf16.h>

#define NNODES 100000
#define NEDGES 1600000
#define IN_F 16
#define HID 128
#define NLAYERS 8
#define BN_EPS 1e-5f
#define BLOBSZ 532480   // ushorts per blob half: 8192 + 16*32768

typedef __attribute__((ext_vector_type(8))) short short8;
typedef __attribute__((ext_vector_type(4))) float f32x4;
typedef __attribute__((ext_vector_type(4))) unsigned int uint32x4;
typedef unsigned short ushort_t;
typedef unsigned int uint_t;

__device__ __forceinline__ ushort_t f2bf(float f) {   // RNE, unbiased
  uint_t u = __builtin_bit_cast(uint_t, f);
  uint_t r = (u + 0x7fffu + ((u >> 16) & 1u)) >> 16;
  return (ushort_t)r;
}
__device__ __forceinline__ float bfl(uint_t u) {
  return __builtin_bit_cast(float, u << 16);
}
__device__ __forceinline__ float bfh(uint_t u) {
  return __builtin_bit_cast(float, u & 0xFFFF0000u);
}
__device__ __forceinline__ void bsplit(float v, ushort_t& h, ushort_t& l) {
  h = f2bf(v);
  float r = v - bfl((uint_t)h);
  l = f2bf(r);
}

// nontemporal helpers (GEMM A/C streams only; agg stays cached — r10 lesson)
__device__ __forceinline__ f32x4 ntl4(const float* p) {
  return __builtin_nontemporal_load((const f32x4*)p);
}
__device__ __forceinline__ void nts1(float v, float* p) {
  __builtin_nontemporal_store(v, p);
}

// cheap truncation split of 8 fp32 -> hi/lo short8 (err <= 2^-16 rel)
__device__ __forceinline__ void split8(const float* v, short8& h8, short8& l8) {
  uint_t hp[4], lp[4];
#pragma unroll
  for (int j = 0; j < 4; ++j) {
    float v0 = v[2 * j], v1 = v[2 * j + 1];
    uint_t u0 = __builtin_bit_cast(uint_t, v0);
    uint_t u1 = __builtin_bit_cast(uint_t, v1);
    uint_t h0 = u0 & 0xFFFF0000u;
    uint_t h1 = u1 & 0xFFFF0000u;
    float r0 = v0 - __builtin_bit_cast(float, h0);
    float r1 = v1 - __builtin_bit_cast(float, h1);
    hp[j] = (h0 >> 16) | h1;
    lp[j] = (__builtin_bit_cast(uint_t, r0) >> 16) |
            (__builtin_bit_cast(uint_t, r1) & 0xFFFF0000u);
  }
  h8 = __builtin_bit_cast(short8, (uint32x4){hp[0], hp[1], hp[2], hp[3]});
  l8 = __builtin_bit_cast(short8, (uint32x4){lp[0], lp[1], lp[2], lp[3]});
}

// ===================== CSR build: 2-level bucket sort (r8 win) =====================
__global__ __launch_bounds__(256) void bhist_kernel(
    const int* __restrict__ dst, int* __restrict__ bucketCnt, int E, int nbk) {
  __shared__ int cnt[256];
  int t = threadIdx.x;
  cnt[t] = 0;
  __syncthreads();
  int base = blockIdx.x * 2048 + t * 8;
#pragma unroll
  for (int j = 0; j < 8; ++j) {
    int i = base + j;
    if (i < E) atomicAdd(&cnt[dst[i] >> 9], 1);
  }
  __syncthreads();
  if (t < nbk && cnt[t]) atomicAdd(&bucketCnt[t], cnt[t]);
}

__global__ void bscan_kernel(const int* __restrict__ bucketCnt, int* __restrict__ bucketBase,
                             int* __restrict__ bucketCur, int* __restrict__ row_ptr,
                             int N, int E, int nbk) {
  __shared__ int s[256];
  int t = threadIdx.x;
  s[t] = (t < nbk) ? bucketCnt[t] : 0;
  __syncthreads();
  for (int off = 1; off < 256; off <<= 1) {
    int v = (t >= off) ? s[t - off] : 0;
    __syncthreads();
    s[t] += v;
    __syncthreads();
  }
  int excl = (t == 0) ? 0 : s[t - 1];
  if (t < nbk) { bucketBase[t] = excl; bucketCur[t] = excl; }
  if (t == nbk) bucketBase[t] = E;
  if (t == 0) row_ptr[N] = E;
}

__global__ __launch_bounds__(256) void bscatter_kernel(
    const int* __restrict__ src, const int* __restrict__ dst,
    int* __restrict__ bucketCur, int2* __restrict__ ebuf, int E, int nbk) {
  __shared__ int cnt[256];
  __shared__ int base_l[256];
  int t = threadIdx.x;
  cnt[t] = 0;
  __syncthreads();
  int base = blockIdx.x * 2048 + t * 8;
  int bj[8], lr[8], dj[8], sj[8];
#pragma unroll
  for (int j = 0; j < 8; ++j) {
    int i = base + j;
    if (i < E) {
      dj[j] = dst[i];
      sj[j] = src[i];
      bj[j] = dj[j] >> 9;
      lr[j] = atomicAdd(&cnt[bj[j]], 1);
    } else bj[j] = -1;
  }
  __syncthreads();
  if (t < nbk) base_l[t] = cnt[t] ? atomicAdd(&bucketCur[t], cnt[t]) : 0;
  __syncthreads();
#pragma unroll
  for (int j = 0; j < 8; ++j)
    if (bj[j] >= 0) ebuf[base_l[bj[j]] + lr[j]] = make_int2(dj[j], sj[j]);
}

__global__ __launch_bounds__(256) void bcsr_kernel(
    const int2* __restrict__ ebuf, const int* __restrict__ bucketBase,
    int* __restrict__ row_ptr, int* __restrict__ colb, int N) {
  __shared__ int h[512];
  __shared__ int cur[512];
  __shared__ int s2[256];
  int b = blockIdx.x, t = threadIdx.x;
  int beg = bucketBase[b], end = bucketBase[b + 1];
  h[t] = 0; h[t + 256] = 0;
  __syncthreads();
  for (int p = beg + t; p < end; p += 256) atomicAdd(&h[ebuf[p].x & 511], 1);
  __syncthreads();
  s2[t] = h[2 * t] + h[2 * t + 1];
  __syncthreads();
  for (int off = 1; off < 256; off <<= 1) {
    int v = (t >= off) ? s2[t - off] : 0;
    __syncthreads();
    s2[t] += v;
    __syncthreads();
  }
  int ep = (t == 0) ? 0 : s2[t - 1];
  cur[2 * t] = ep;
  cur[2 * t + 1] = ep + h[2 * t];
  int dg = (b << 9) + 2 * t;
  if (dg < N) row_ptr[dg] = beg + cur[2 * t];
  if (dg + 1 < N) row_ptr[dg + 1] = beg + cur[2 * t + 1];
  __syncthreads();
  for (int p = beg + t; p < end; p += 256) {
    int2 e2 = ebuf[p];
    int pos = beg + atomicAdd(&cur[e2.x & 511], 1);
    colb[pos] = e2.y;
  }
}

// =================== weight pre-convert: split hi/lo MFMA-frag blobs ===================
__global__ void preconv_kernel(const float* __restrict__ W1_0, const float* __restrict__ W1,
                               const float* __restrict__ W2, const float* __restrict__ Wr1,
                               ushort_t* __restrict__ WB) {
  int g = blockIdx.y;
  int e = blockIdx.x * 256 + threadIdx.x;
  int KP = (g == 0) ? 32 : 128;
  if (e >= KP * 128) return;
  int k = e >> 7, n = e & 127;
  float v;
  if (g == 0) v = (k < 16) ? W1_0[k * 128 + n] : 0.0f;
  else if (g <= 7) v = W1[(size_t)(g - 1) * 16384 + e];
  else if (g <= 15) v = W2[(size_t)(g - 8) * 16384 + e];
  else v = Wr1[e];
  size_t base = (g == 0) ? 0 : (8192 + (size_t)(g - 1) * 32768);
  int unit = ((k >> 5) << 9) + ((n >> 4) << 6) + (n & 15) + (((k >> 3) & 3) << 4);
  ushort_t h, l;
  bsplit(v, h, l);
  WB[base + (size_t)unit * 8 + (k & 7)] = h;
  WB[BLOBSZ + base + (size_t)unit * 8 + (k & 7)] = l;
}

// ============================ layer-0 aggregation (F=16, fp32) ============================
__global__ __launch_bounds__(256) void agg16_kernel(
    const float* __restrict__ X, const int* __restrict__ rp, const int* __restrict__ colb,
    const float* __restrict__ eps, float* __restrict__ Z, int N) {
  int g = threadIdx.x >> 3;
  int l = threadIdx.x & 7;
  int n = blockIdx.x * 32 + g;
  if (n >= N) return;
  float e = 1.0f + eps[0];
  const float2* X2 = (const float2*)X;
  float2 self = X2[(size_t)n * 8 + l];
  float2 acc = make_float2(self.x * e, self.y * e);
  float2 acc2 = make_float2(0.0f, 0.0f);
  int beg = rp[n], end = rp[n + 1];
  int p = beg;
  for (; p + 4 <= end; p += 4) {
    int s0 = colb[p], s1 = colb[p + 1], s2 = colb[p + 2], s3 = colb[p + 3];
    float2 v0 = X2[(size_t)s0 * 8 + l];
    float2 v1 = X2[(size_t)s1 * 8 + l];
    float2 v2 = X2[(size_t)s2 * 8 + l];
    float2 v3 = X2[(size_t)s3 * 8 + l];
    acc.x += v0.x; acc.y += v0.y;
    acc2.x += v1.x; acc2.y += v1.y;
    acc.x += v2.x; acc.y += v2.y;
    acc2.x += v3.x; acc2.y += v3.y;
  }
  for (; p < end; ++p) {
    int s = colb[p];
    float2 v = X2[(size_t)s * 8 + l];
    acc.x += v.x; acc.y += v.y;
  }
  acc.x += acc2.x; acc.y += acc2.y;
  ((float2*)Z)[(size_t)n * 8 + l] = acc;
}

// layers 1..7: Y bf16, per-node wave blocks — r9 EXACT form (measured floor, 90 us).
// r8: never fuse w/ GEMM. r10: nt regressed. r12: grid-stride regressed. r13: this form ✓.
// smode: 0 = no skip, 1 = SKIP store (first touch at L=2 — also kills the 51MB memset),
//        2 = SKIP += (L=4,6).
__global__ __launch_bounds__(256) void agg128_kernel(
    const ushort_t* __restrict__ Y, const float* __restrict__ av, const float* __restrict__ cv,
    const int* __restrict__ rp, const int* __restrict__ colb,
    const float* __restrict__ eps, int layer, float* __restrict__ Z,
    float* __restrict__ SKIP, int smode, int N) {
  int wv = threadIdx.x >> 6;
  int lane = threadIdx.x & 63;
  int n = blockIdx.x * 4 + wv;
  if (n >= N) return;
  float e = 1.0f + eps[layer];
  float2 a2 = *(const float2*)(av + lane * 2);
  float2 c2 = *(const float2*)(cv + lane * 2);
  const uint_t* Yu = (const uint_t*)Y;
  uint_t sv = Yu[(size_t)n * 64 + lane];
  float hx = fmaxf(fmaf(a2.x, bfl(sv), c2.x), 0.0f);
  float hy = fmaxf(fmaf(a2.y, bfh(sv), c2.y), 0.0f);
  if (smode == 1) {
    ((float2*)SKIP)[(size_t)n * 64 + lane] = make_float2(hx, hy);
  } else if (smode == 2) {
    float2* S2 = (float2*)SKIP;
    float2 s = S2[(size_t)n * 64 + lane];
    s.x += hx; s.y += hy;
    S2[(size_t)n * 64 + lane] = s;
  }
  float ax = hx * e, ay = hy * e;
  float bx = 0.0f, by = 0.0f, cx = 0.0f, cy = 0.0f, dx = 0.0f, dy = 0.0f;
  int beg = rp[n], end = rp[n + 1];
  int p = beg;
  for (; p + 8 <= end; p += 8) {
    int s0 = colb[p], s1 = colb[p + 1], s2 = colb[p + 2], s3 = colb[p + 3];
    int s4 = colb[p + 4], s5 = colb[p + 5], s6 = colb[p + 6], s7 = colb[p + 7];
    uint_t v0 = Yu[(size_t)s0 * 64 + lane];
    uint_t v1 = Yu[(size_t)s1 * 64 + lane];
    uint_t v2 = Yu[(size_t)s2 * 64 + lane];
    uint_t v3 = Yu[(size_t)s3 * 64 + lane];
    uint_t v4 = Yu[(size_t)s4 * 64 + lane];
    uint_t v5 = Yu[(size_t)s5 * 64 + lane];
    uint_t v6 = Yu[(size_t)s6 * 64 + lane];
    uint_t v7 = Yu[(size_t)s7 * 64 + lane];
    ax += fmaxf(fmaf(a2.x, bfl(v0), c2.x), 0.0f);
    ay += fmaxf(fmaf(a2.y, bfh(v0), c2.y), 0.0f);
    bx += fmaxf(fmaf(a2.x, bfl(v1), c2.x), 0.0f);
    by += fmaxf(fmaf(a2.y, bfh(v1), c2.y), 0.0f);
    cx += fmaxf(fmaf(a2.x, bfl(v2), c2.x), 0.0f);
    cy += fmaxf(fmaf(a2.y, bfh(v2), c2.y), 0.0f);
    dx += fmaxf(fmaf(a2.x, bfl(v3), c2.x), 0.0f);
    dy += fmaxf(fmaf(a2.y, bfh(v3), c2.y), 0.0f);
    ax += fmaxf(fmaf(a2.x, bfl(v4), c2.x), 0.0f);
    ay += fmaxf(fmaf(a2.y, bfh(v4), c2.y), 0.0f);
    bx += fmaxf(fmaf(a2.x, bfl(v5), c2.x), 0.0f);
    by += fmaxf(fmaf(a2.y, bfh(v5), c2.y), 0.0f);
    cx += fmaxf(fmaf(a2.x, bfl(v6), c2.x), 0.0f);
    cy += fmaxf(fmaf(a2.y, bfh(v6), c2.y), 0.0f);
    dx += fmaxf(fmaf(a2.x, bfl(v7), c2.x), 0.0f);
    dy += fmaxf(fmaf(a2.y, bfh(v7), c2.y), 0.0f);
  }
  for (; p < end; ++p) {
    int s = colb[p];
    uint_t v = Yu[(size_t)s * 64 + lane];
    ax += fmaxf(fmaf(a2.x, bfl(v), c2.x), 0.0f);
    ay += fmaxf(fmaf(a2.y, bfh(v), c2.y), 0.0f);
  }
  ax += bx + cx + dx;
  ay += by + cy + dy;
  ((float2*)Z)[(size_t)n * 64 + lane] = make_float2(ax, ay);
}

// ======== LDS-free split-bf16 MFMA GEMM — r10 EXACT form (measured best GEMM) ========
// 128-row tile, direct per-lane A fragments (r11 LDS-staged: worse; r13 64-row: worse).
// nt A/C streams; B-blob + YB cached. Quad-shuffle epilogue + relaxed atomics (r6/r10).
// MODE 0: op=A(fp32)   MODE 1: op=relu(pa*A+pc)
// MODE 2: op=0.25*(A(fp32 SKIP) + relu(pa*A2(bf16)+pc))   MODE 3: A fp32 [M,16], K=32 pad
// OUT 0: C fp32 (nt)   OUT 1: C bf16 (cached — next gather's hot buffer)
template <int KTOT, int MODE, int OUT>
__global__ __launch_bounds__(256, 4) void gemm_mfma(
    const float* __restrict__ A, const ushort_t* __restrict__ A2u,
    const ushort_t* __restrict__ Bhi, const ushort_t* __restrict__ Blo,
    const float* __restrict__ bias,
    const float* __restrict__ pa, const float* __restrict__ pc,
    void* __restrict__ Cv,
    float* __restrict__ gsum, float* __restrict__ gsq,
    float* __restrict__ aout, float* __restrict__ cout, int* __restrict__ cnt,
    const float* __restrict__ gamma, const float* __restrict__ beta,
    float invN, int M, int nb) {
  __shared__ float s_part[4][256];   // [wave][0..127]=sum, [128..255]=sumsq
  __shared__ int s_last;
  const int tid = threadIdx.x;
  const int w = tid >> 6;
  const int lane = tid & 63;
  const int ln = lane & 15;
  const int quad = lane >> 4;
  const int brow = blockIdx.x * 128;
  constexpr int AST = (MODE == 3) ? 16 : KTOT;

  int r0 = brow + (w << 5) + ln;       if (r0 >= M) r0 = M - 1;
  int r1 = brow + (w << 5) + 16 + ln;  if (r1 >= M) r1 = M - 1;

  f32x4 acc[2][8];
#pragma unroll
  for (int rt = 0; rt < 2; ++rt)
#pragma unroll
    for (int ct = 0; ct < 8; ++ct) acc[rt][ct] = (f32x4){0.0f, 0.0f, 0.0f, 0.0f};

  constexpr int KC = KTOT / 32;
#pragma unroll
  for (int kcl = 0; kcl < KC; ++kcl) {
    const int kb = (kcl << 5) + (quad << 3);
    float e0[8], e1[8];
    if constexpr (MODE == 3) {
      if (kb < 16) {
        f32x4 a0 = ntl4(A + (size_t)r0 * AST + kb);
        f32x4 a1 = ntl4(A + (size_t)r0 * AST + kb + 4);
        e0[0] = a0.x; e0[1] = a0.y; e0[2] = a0.z; e0[3] = a0.w;
        e0[4] = a1.x; e0[5] = a1.y; e0[6] = a1.z; e0[7] = a1.w;
        f32x4 b0 = ntl4(A + (size_t)r1 * AST + kb);
        f32x4 b1 = ntl4(A + (size_t)r1 * AST + kb + 4);
        e1[0] = b0.x; e1[1] = b0.y; e1[2] = b0.z; e1[3] = b0.w;
        e1[4] = b1.x; e1[5] = b1.y; e1[6] = b1.z; e1[7] = b1.w;
      } else {
#pragma unroll
        for (int j = 0; j < 8; ++j) { e0[j] = 0.0f; e1[j] = 0.0f; }
      }
    } else {
      f32x4 a0 = ntl4(A + (size_t)r0 * AST + kb);
      f32x4 a1 = ntl4(A + (size_t)r0 * AST + kb + 4);
      f32x4 b0 = ntl4(A + (size_t)r1 * AST + kb);
      f32x4 b1 = ntl4(A + (size_t)r1 * AST + kb + 4);
      e0[0] = a0.x; e0[1] = a0.y; e0[2] = a0.z; e0[3] = a0.w;
      e0[4] = a1.x; e0[5] = a1.y; e0[6] = a1.z; e0[7] = a1.w;
      e1[0] = b0.x; e1[1] = b0.y; e1[2] = b0.z; e1[3] = b0.w;
      e1[4] = b1.x; e1[5] = b1.y; e1[6] = b1.z; e1[7] = b1.w;
      if constexpr (MODE == 1) {
        float4 p0 = *(const float4*)(pa + kb);
        float4 p1 = *(const float4*)(pa + kb + 4);
        float4 q0 = *(const float4*)(pc + kb);
        float4 q1 = *(const float4*)(pc + kb + 4);
        float pp[8] = {p0.x, p0.y, p0.z, p0.w, p1.x, p1.y, p1.z, p1.w};
        float qq[8] = {q0.x, q0.y, q0.z, q0.w, q1.x, q1.y, q1.z, q1.w};
#pragma unroll
        for (int j = 0; j < 8; ++j) {
          e0[j] = fmaxf(fmaf(pp[j], e0[j], qq[j]), 0.0f);
          e1[j] = fmaxf(fmaf(pp[j], e1[j], qq[j]), 0.0f);
        }
      } else if constexpr (MODE == 2) {
        uint4 ya = *(const uint4*)(A2u + (size_t)r0 * 128 + kb);
        uint4 yb = *(const uint4*)(A2u + (size_t)r1 * 128 + kb);
        float4 p0 = *(const float4*)(pa + kb);
        float4 p1 = *(const float4*)(pa + kb + 4);
        float4 q0 = *(const float4*)(pc + kb);
        float4 q1 = *(const float4*)(pc + kb + 4);
        float y0a[8] = {bfl(ya.x), bfh(ya.x), bfl(ya.y), bfh(ya.y),
                        bfl(ya.z), bfh(ya.z), bfl(ya.w), bfh(ya.w)};
        float y1a[8] = {bfl(yb.x), bfh(yb.x), bfl(yb.y), bfh(yb.y),
                        bfl(yb.z), bfh(yb.z), bfl(yb.w), bfh(yb.w)};
        float pp[8] = {p0.x, p0.y, p0.z, p0.w, p1.x, p1.y, p1.z, p1.w};
        float qq[8] = {q0.x, q0.y, q0.z, q0.w, q1.x, q1.y, q1.z, q1.w};
#pragma unroll
        for (int j = 0; j < 8; ++j) {
          e0[j] = 0.25f * (e0[j] + fmaxf(fmaf(pp[j], y0a[j], qq[j]), 0.0f));
          e1[j] = 0.25f * (e1[j] + fmaxf(fmaf(pp[j], y1a[j], qq[j]), 0.0f));
        }
      }
    }
    short8 a0h, a0l, a1h, a1l;
    split8(e0, a0h, a0l);
    split8(e1, a1h, a1l);
    const ushort_t* bh_base = Bhi + (((size_t)(kcl << 9) + lane) << 3);
    const ushort_t* bl_base = Blo + (((size_t)(kcl << 9) + lane) << 3);
#pragma unroll
    for (int ct = 0; ct < 8; ++ct) {
      short8 bh = *(const short8*)(bh_base + (ct << 9));
      short8 bl = *(const short8*)(bl_base + (ct << 9));
      acc[0][ct] = __builtin_amdgcn_mfma_f32_16x16x32_bf16(a0h, bh, acc[0][ct], 0, 0, 0);
      acc[0][ct] = __builtin_amdgcn_mfma_f32_16x16x32_bf16(a0l, bh, acc[0][ct], 0, 0, 0);
      acc[0][ct] = __builtin_amdgcn_mfma_f32_16x16x32_bf16(a0h, bl, acc[0][ct], 0, 0, 0);
      acc[1][ct] = __builtin_amdgcn_mfma_f32_16x16x32_bf16(a1h, bh, acc[1][ct], 0, 0, 0);
      acc[1][ct] = __builtin_amdgcn_mfma_f32_16x16x32_bf16(a1l, bh, acc[1][ct], 0, 0, 0);
      acc[1][ct] = __builtin_amdgcn_mfma_f32_16x16x32_bf16(a1h, bl, acc[1][ct], 0, 0, 0);
    }
  }

  // ---- epilogue: bias, store, quad-shuffle stats ----
#pragma unroll
  for (int ct = 0; ct < 8; ++ct) {
    int col = (ct << 4) + ln;
    float bsc = bias[col];
    float csum = 0.0f, csq = 0.0f;
#pragma unroll
    for (int rt = 0; rt < 2; ++rt) {
#pragma unroll
      for (int i = 0; i < 4; ++i) {
        int row = brow + (w << 5) + (rt << 4) + (quad << 2) + i;
        if (row < M) {
          float y = acc[rt][ct][i] + bsc;
          csum += y; csq += y * y;
          if constexpr (OUT == 0) {
            nts1(y, &((float*)Cv)[(size_t)row * 128 + col]);
          } else {
            ((ushort_t*)Cv)[(size_t)row * 128 + col] = f2bf(y);
          }
        }
      }
    }
    csum += __shfl_xor(csum, 16, 64);
    csum += __shfl_xor(csum, 32, 64);
    csq += __shfl_xor(csq, 16, 64);
    csq += __shfl_xor(csq, 32, 64);
    if (quad == 0) {
      s_part[w][col] = csum;
      s_part[w][128 + col] = csq;
    }
  }
  __syncthreads();
  if (tid < 128) {
    float s = s_part[0][tid] + s_part[1][tid] + s_part[2][tid] + s_part[3][tid];
    float q = s_part[0][128 + tid] + s_part[1][128 + tid] +
              s_part[2][128 + tid] + s_part[3][128 + tid];
    atomicAdd(&gsum[tid], s);   // relaxed device-scope, no flush (r6)
    atomicAdd(&gsq[tid], q);
  }
  __syncthreads();   // drains vmcnt -> stats atomics complete
  if (tid == 0) {
    int v = __hip_atomic_fetch_add(cnt, 1, __ATOMIC_RELAXED, __HIP_MEMORY_SCOPE_AGENT);
    s_last = (v == nb - 1) ? 1 : 0;
  }
  __syncthreads();
  if (s_last && tid < 128) {
    float s = __hip_atomic_load(&gsum[tid], __ATOMIC_RELAXED, __HIP_MEMORY_SCOPE_AGENT);
    float q = __hip_atomic_load(&gsq[tid], __ATOMIC_RELAXED, __HIP_MEMORY_SCOPE_AGENT);
    float mu = s * invN;
    float var = q * invN - mu * mu;
    float sc = gamma[tid] * rsqrtf(var + BN_EPS);
    aout[tid] = sc;
    cout[tid] = beta[tid] - sc * mu;
  }
}

// ============================ regressor head ============================
__global__ __launch_bounds__(256) void finaldot_kernel(
    const float* __restrict__ Y, const float* __restrict__ a, const float* __restrict__ c,
    const float* __restrict__ Wr2, const float* __restrict__ br2,
    float* __restrict__ out, int N) {
  int wv = threadIdx.x >> 6;
  int lane = threadIdx.x & 63;
  int n = blockIdx.x * 4 + wv;
  if (n >= N) return;
  float2 y = *(const float2*)(Y + (size_t)n * HID + lane * 2);
  int c0 = lane * 2;
  float s = fmaxf(fmaf(a[c0], y.x, c[c0]), 0.0f) * Wr2[c0] +
            fmaxf(fmaf(a[c0 + 1], y.y, c[c0 + 1]), 0.0f) * Wr2[c0 + 1];
  for (int off = 32; off > 0; off >>= 1) s += __shfl_down(s, off, 64);
  if (lane == 0) out[n] = 1.0f / (1.0f + expf(-(s + br2[0])));
}

// ============================ launch ============================
extern "C" void kernel_launch(void* const* d_in, const int* in_sizes, int n_in,
                              void* d_out, int out_size, void* d_ws, size_t ws_size,
                              hipStream_t stream) {
  const float* x     = (const float*)d_in[0];
  const int*   ei    = (const int*)d_in[1];
  const float* eps   = (const float*)d_in[2];
  const float* W1_0  = (const float*)d_in[3];
  const float* b1_0  = (const float*)d_in[4];
  const float* W1    = (const float*)d_in[5];
  const float* b1    = (const float*)d_in[6];
  const float* g_in  = (const float*)d_in[7];
  const float* be_in = (const float*)d_in[8];
  const float* W2    = (const float*)d_in[9];
  const float* b2    = (const float*)d_in[10];
  const float* g_out = (const float*)d_in[11];
  const float* be_out= (const float*)d_in[12];
  const float* Wr1   = (const float*)d_in[13];
  const float* br1   = (const float*)d_in[14];
  const float* gr    = (const float*)d_in[15];
  const float* ber   = (const float*)d_in[16];
  const float* Wr2   = (const float*)d_in[17];
  const float* br2   = (const float*)d_in[18];
  float* out = (float*)d_out;

  const int N = in_sizes[0] / IN_F;   // 100000
  const int E = in_sizes[1] / 2;      // 1600000
  const int* srcv = ei;
  const int* dstv = ei + E;
  const int nbk = (N + 511) >> 9;     // 196 buckets

  // workspace carve
  float* X0    = (float*)d_ws;                  // [N][128] fp32 (Z / H1, in-place)
  float* SKIP  = X0 + (size_t)N * HID;          // [N][128] fp32 (layer-0 temp, then skip)
  ushort_t* YB = (ushort_t*)(SKIP + (size_t)N * HID);  // [N][128] bf16 Y (hot gather target)
  int* colb    = (int*)(YB + (size_t)N * HID);
  int* row_ptr = colb + E;
  int2* ebuf   = (int2*)(row_ptr + (N + 4));
  int* bucketCnt  = (int*)(ebuf + E);
  int* bucketBase = bucketCnt + 256;
  int* bucketCur  = bucketBase + 260;
  float* arena = (float*)(bucketCur + 256);     // 17 slots x 640 floats
  ushort_t* WB = (ushort_t*)(arena + 17 * 640); // hi blob | lo blob

  hipMemsetAsync(bucketCnt, 0, sizeof(int) * 256, stream);
  hipMemsetAsync(arena, 0, sizeof(float) * 17 * 640, stream);

  // CSR build (bucket sort)
  int nbE = (E + 2047) / 2048;
  bhist_kernel<<<nbE, 256, 0, stream>>>(dstv, bucketCnt, E, nbk);
  bscan_kernel<<<1, 256, 0, stream>>>(bucketCnt, bucketBase, bucketCur, row_ptr, N, E, nbk);
  bscatter_kernel<<<nbE, 256, 0, stream>>>(srcv, dstv, bucketCur, ebuf, E, nbk);
  bcsr_kernel<<<nbk, 256, 0, stream>>>(ebuf, bucketBase, row_ptr, colb, N);
  preconv_kernel<<<dim3(64, 17), 256, 0, stream>>>(W1_0, W1, W2, Wr1, WB);

  const int gg = (N + 127) / 128;   // 128-row tiles (r10 optimum)
  const float invN = 1.0f / (float)N;
#define SLOT(s) (arena + (s) * 640)
#define SSUM(s) SLOT(s)
#define SSQ(s)  (SLOT(s) + 128)
#define SA(s)   (SLOT(s) + 256)
#define SC(s)   (SLOT(s) + 384)
#define SCNT(s) ((int*)(SLOT(s) + 512))
#define WBH(g)  (WB + ((g) == 0 ? 0 : (8192 + (size_t)((g) - 1) * 32768)))
#define WBL(g)  (WBH(g) + BLOBSZ)

  // ---- layer 0 ----  agg16: x -> X0[N,16]; g0a: X0 -> SKIP(temp); g0b: SKIP -> YB bf16
  agg16_kernel<<<(N + 31) / 32, 256, 0, stream>>>(x, row_ptr, colb, eps, X0, N);
  gemm_mfma<32, 3, 0><<<gg, 256, 0, stream>>>(
      X0, nullptr, WBH(0), WBL(0), b1_0, nullptr, nullptr, SKIP,
      SSUM(0), SSQ(0), SA(0), SC(0), SCNT(0), g_in, be_in, invN, N, gg);
  gemm_mfma<128, 1, 1><<<gg, 256, 0, stream>>>(
      SKIP, nullptr, WBH(8), WBL(8), b2, SA(0), SC(0), YB,
      SSUM(1), SSQ(1), SA(1), SC(1), SCNT(1), g_out, be_out, invN, N, gg);
  // No SKIP memset: L=2's agg does a plain store (smode=1) covering all N*128 elements.

  // ---- layers 1..7 ----  agg: YB->X0 (fp32 Z); gemm1: X0->X0 in place; gemm2: X0->YB
  for (int L = 1; L < NLAYERS; ++L) {
    int sp = 2 * L - 1;
    int s0 = 2 * L, s1 = 2 * L + 1;
    // skip taps h_1,h_3,h_5 at L=2,4,6 (h_7 folded in regressor). First tap stores.
    int smode = ((L - 1) & 1) ? ((L == 2) ? 1 : 2) : 0;
    agg128_kernel<<<(N + 3) / 4, 256, 0, stream>>>(
        YB, SA(sp), SC(sp), row_ptr, colb, eps, L, X0, SKIP, smode, N);
    gemm_mfma<128, 0, 0><<<gg, 256, 0, stream>>>(
        X0, nullptr, WBH(L), WBL(L), b1 + (size_t)(L - 1) * HID, nullptr, nullptr, X0,
        SSUM(s0), SSQ(s0), SA(s0), SC(s0), SCNT(s0),
        g_in + (size_t)L * HID, be_in + (size_t)L * HID, invN, N, gg);
    gemm_mfma<128, 1, 1><<<gg, 256, 0, stream>>>(
        X0, nullptr, WBH(8 + L), WBL(8 + L), b2 + (size_t)L * HID, SA(s0), SC(s0), YB,
        SSUM(s1), SSQ(s1), SA(s1), SC(s1), SCNT(s1),
        g_out + (size_t)L * HID, be_out + (size_t)L * HID, invN, N, gg);
  }
  // Y7 in YB (bf16), slot 15 holds its outer-BN params

  // ---- regressor: op = 0.25*(SKIP + relu(a7*Y7+c7)) ----
  gemm_mfma<128, 2, 0><<<gg, 256, 0, stream>>>(
      SKIP, YB, WBH(16), WBL(16), br1, SA(15), SC(15), X0,
      SSUM(16), SSQ(16), SA(16), SC(16), SCNT(16), gr, ber, invN, N, gg);
  finaldot_kernel<<<(N + 3) / 4, 256, 0, stream>>>(X0, SA(16), SC(16), Wr2, br2, out, N);
#undef SLOT
#undef SSUM
#undef SSQ
#undef SA
#undef SC
#undef SCNT
#undef WBH
#undef WBL
}